// Round 2
// baseline (188.327 us; speedup 1.0000x reference)
//
#include <hip/hip_runtime.h>
#include <hip/hip_bf16.h>
#include <stdint.h>

#define N_NODES 10000
#define N_EDGES 320000
#define DD 256

typedef __attribute__((ext_vector_type(4))) float f32x4;
typedef __attribute__((ext_vector_type(8))) short short8;
typedef __attribute__((ext_vector_type(4))) short short4v;

__device__ __forceinline__ short f2b(float f) {
  unsigned u = __builtin_bit_cast(unsigned, f);
  u += 0x7fffu + ((u >> 16) & 1u);  // round-to-nearest-even
  return (short)(u >> 16);
}

// x [10000,256] f32 -> bf16
__global__ __launch_bounds__(256) void k_conv_x(const float* __restrict__ x,
                                                short* __restrict__ xb) {
  int i = (blockIdx.x * 256 + threadIdx.x) * 4;
  f32x4 v = *(const f32x4*)(x + i);
  short4v o;
  o[0] = f2b(v[0]); o[1] = f2b(v[1]); o[2] = f2b(v[2]); o[3] = f2b(v[3]);
  *(short4v*)(xb + i) = o;
}

// Bb[n][k] = bf16( n<256 ? W[k][n] : M[k][n-256] )   (transposed so GEMM stages rows)
__global__ __launch_bounds__(256) void k_conv_B(const float* __restrict__ W,
                                                const float* __restrict__ M,
                                                short* __restrict__ Bb) {
  int n = blockIdx.x;   // 0..511
  int k = threadIdx.x;  // 0..255
  float v = (n < DD) ? W[k * DD + n] : M[k * DD + (n - DD)];
  Bb[n * DD + k] = f2b(v);
}

// T[m][n] (n<256: self=x@W, n>=256: msg=x@M), bf16 MFMA, tile 64x64, K staged in 2x128
#define LDK 136  // 128 + 8 bf16 pad: row stride 272B

__global__ __launch_bounds__(256) void k_gemm(const short* __restrict__ xb,
                                              const short* __restrict__ Bb,
                                              float* __restrict__ T) {
  __shared__ short As[64 * LDK];
  __shared__ short Bs[64 * LDK];
  const int m0 = blockIdx.x * 64, n0 = blockIdx.y * 64;
  const int tid = threadIdx.x;
  const int wave = tid >> 6, lane = tid & 63;
  const int wr = (wave >> 1) * 32, wc = (wave & 1) * 32;
  const int lr = lane & 15, lk = (lane >> 4) * 8;
  f32x4 acc00 = {0,0,0,0}, acc01 = {0,0,0,0}, acc10 = {0,0,0,0}, acc11 = {0,0,0,0};

  for (int ko = 0; ko < 256; ko += 128) {
    // stage 64 rows x 128 bf16 for A and B: 64*128/8 = 1024 chunks of 16B, 4 per thread
    #pragma unroll
    for (int c = tid; c < 1024; c += 256) {
      int row = c >> 4, col = (c & 15) * 8;   // 16 chunks/row * 8 elems = 128 cols
      int gm = m0 + row;
      short8 va = {0,0,0,0,0,0,0,0};
      if (gm < N_NODES) va = *(const short8*)(xb + gm * DD + ko + col);
      *(short8*)(&As[row * LDK + col]) = va;
      *(short8*)(&Bs[row * LDK + col]) = *(const short8*)(Bb + (n0 + row) * DD + ko + col);
    }
    __syncthreads();
    #pragma unroll
    for (int kk = 0; kk < 128; kk += 32) {
      short8 a0 = *(const short8*)(&As[(wr + lr) * LDK + kk + lk]);
      short8 a1 = *(const short8*)(&As[(wr + 16 + lr) * LDK + kk + lk]);
      short8 b0 = *(const short8*)(&Bs[(wc + lr) * LDK + kk + lk]);
      short8 b1 = *(const short8*)(&Bs[(wc + 16 + lr) * LDK + kk + lk]);
      acc00 = __builtin_amdgcn_mfma_f32_16x16x32_bf16(a0, b0, acc00, 0, 0, 0);
      acc01 = __builtin_amdgcn_mfma_f32_16x16x32_bf16(a0, b1, acc01, 0, 0, 0);
      acc10 = __builtin_amdgcn_mfma_f32_16x16x32_bf16(a1, b0, acc10, 0, 0, 0);
      acc11 = __builtin_amdgcn_mfma_f32_16x16x32_bf16(a1, b1, acc11, 0, 0, 0);
    }
    __syncthreads();
  }

  // D layout: col = lane&15, row = (lane>>4)*4 + reg  [verified m89/m91]
  const int rb = (lane >> 4) * 4;
  const int cb = lane & 15;
  #pragma unroll
  for (int r = 0; r < 4; r++) {
    int gm0 = m0 + wr + rb + r;
    int gm1 = gm0 + 16;
    int gc = n0 + wc + cb;
    if (gm0 < N_NODES) {
      T[gm0 * 512 + gc]      = acc00[r];
      T[gm0 * 512 + gc + 16] = acc01[r];
    }
    if (gm1 < N_NODES) {
      T[gm1 * 512 + gc]      = acc10[r];
      T[gm1 * 512 + gc + 16] = acc11[r];
    }
  }
}

__global__ __launch_bounds__(256) void k_hist(const int* __restrict__ dst,
                                              int* __restrict__ deg) {
  int e = blockIdx.x * 256 + threadIdx.x;
  if (e < N_EDGES) atomicAdd(&deg[dst[e]], 1);
}

// exclusive scan of deg[10000] -> rowstart, cursor (single block, 1024 threads x 10 elems)
__global__ __launch_bounds__(1024) void k_scan(const int* __restrict__ deg,
                                               int* __restrict__ rowstart,
                                               int* __restrict__ cursor) {
  __shared__ int wsum[16];
  const int t = threadIdx.x;
  const int base = t * 10;
  int local[10];
  int s = 0;
  #pragma unroll
  for (int i = 0; i < 10; i++) {
    int idx = base + i;
    int dv = (idx < N_NODES) ? deg[idx] : 0;
    local[i] = s;
    s += dv;
  }
  const int lane = t & 63, wv = t >> 6;
  int v = s;
  #pragma unroll
  for (int off = 1; off < 64; off <<= 1) {
    int u = __shfl_up(v, off);
    if (lane >= off) v += u;
  }
  if (lane == 63) wsum[wv] = v;
  __syncthreads();
  if (t < 16) {
    int a = wsum[t];
    int vv = a;
    #pragma unroll
    for (int off = 1; off < 16; off <<= 1) {
      int u = __shfl_up(vv, off);
      if (t >= off) vv += u;
    }
    wsum[t] = vv - a;  // exclusive wave-sum prefix
  }
  __syncthreads();
  const int excl = (v - s) + wsum[wv];
  #pragma unroll
  for (int i = 0; i < 10; i++) {
    int idx = base + i;
    if (idx < N_NODES) {
      int r = excl + local[i];
      rowstart[idx] = r;
      cursor[idx] = r;
    }
  }
}

__global__ __launch_bounds__(256) void k_scatter(const int* __restrict__ src,
                                                 const int* __restrict__ dst,
                                                 int* __restrict__ cursor,
                                                 int* __restrict__ srcs) {
  int e = blockIdx.x * 256 + threadIdx.x;
  if (e < N_EDGES) {
    int p = atomicAdd(&cursor[dst[e]], 1);
    srcs[p] = src[e];
  }
}

// one wave per destination node: acc = self(row) + sum msg[srcs]; relu; store
__global__ __launch_bounds__(256) void k_agg(const float* __restrict__ T,
                                             const int* __restrict__ rowstart,
                                             const int* __restrict__ deg,
                                             const int* __restrict__ srcs,
                                             float* __restrict__ out) {
  const int wave = threadIdx.x >> 6, lane = threadIdx.x & 63;
  const int node = blockIdx.x * 4 + wave;
  const int col = lane * 4;
  f32x4 acc = *(const f32x4*)(T + node * 512 + col);  // self term (cols 0..255)
  const int rs = rowstart[node];
  const int d = deg[node];
  for (int e = 0; e < d; e++) {
    int s = srcs[rs + e];
    acc += *(const f32x4*)(T + s * 512 + 256 + col);  // msg term (cols 256..511)
  }
  f32x4 r;
  r[0] = fmaxf(acc[0], 0.f);
  r[1] = fmaxf(acc[1], 0.f);
  r[2] = fmaxf(acc[2], 0.f);
  r[3] = fmaxf(acc[3], 0.f);
  *(f32x4*)(out + node * DD + col) = r;
}

extern "C" void kernel_launch(void* const* d_in, const int* in_sizes, int n_in,
                              void* d_out, int out_size, void* d_ws, size_t ws_size,
                              hipStream_t stream) {
  const float* x = (const float*)d_in[0];
  const float* W = (const float*)d_in[1];
  const float* M = (const float*)d_in[2];
  const int* esrc = (const int*)d_in[3];
  const int* edst = (const int*)d_in[4];
  float* out = (float*)d_out;

  char* w = (char*)d_ws;
  short* xb = (short*)w;                    // 10000*256*2   = 5,120,000 B
  short* Bb = (short*)(w + 5120000);        // 512*256*2     =   262,144 B
  float* T  = (float*)(w + 5382144);        // 10000*512*4   = 20,480,000 B
  int* deg      = (int*)(w + 25862144);     // 40,000 B
  int* rowstart = deg + N_NODES;            // 40,000 B
  int* cursor   = rowstart + N_NODES;       // 40,000 B
  int* srcs     = cursor + N_NODES;         // 1,280,000 B  (total ~27.3 MB)

  hipMemsetAsync(deg, 0, N_NODES * sizeof(int), stream);
  k_conv_x<<<2500, 256, 0, stream>>>(x, xb);
  k_conv_B<<<512, 256, 0, stream>>>(W, M, Bb);
  k_gemm<<<dim3(157, 8), 256, 0, stream>>>(xb, Bb, T);
  k_hist<<<1250, 256, 0, stream>>>(edst, deg);
  k_scan<<<1, 1024, 0, stream>>>(deg, rowstart, cursor);
  k_scatter<<<1250, 256, 0, stream>>>(esrc, edst, cursor, srcs);
  k_agg<<<2500, 256, 0, stream>>>(T, rowstart, deg, srcs, out);
}

// Round 3
// 158.505 us; speedup vs baseline: 1.1881x; 1.1881x over previous
//
#include <hip/hip_runtime.h>
#include <hip/hip_bf16.h>
#include <stdint.h>

#define N_NODES 10000
#define N_EDGES 320000
#define DD 256

typedef __attribute__((ext_vector_type(4))) float f32x4;
typedef __attribute__((ext_vector_type(8))) short short8;
typedef __attribute__((ext_vector_type(4))) short short4v;

__device__ __forceinline__ short f2b(float f) {
  unsigned u = __builtin_bit_cast(unsigned, f);
  u += 0x7fffu + ((u >> 16) & 1u);  // round-to-nearest-even
  return (short)(u >> 16);
}
__device__ __forceinline__ float b2f(short s) {
  return __builtin_bit_cast(float, ((unsigned)(unsigned short)s) << 16);
}

// x [10000,256] f32 -> bf16
__global__ __launch_bounds__(256) void k_conv_x(const float* __restrict__ x,
                                                short* __restrict__ xb) {
  int i = (blockIdx.x * 256 + threadIdx.x) * 4;
  f32x4 v = *(const f32x4*)(x + i);
  short4v o;
  o[0] = f2b(v[0]); o[1] = f2b(v[1]); o[2] = f2b(v[2]); o[3] = f2b(v[3]);
  *(short4v*)(xb + i) = o;
}

// Bb[n][k] = bf16( k<256 ? W[k][n] : M[k-256][n] ), n=0..255, k=0..511 (B^T for staging)
__global__ __launch_bounds__(256) void k_conv_B(const float* __restrict__ W,
                                                const float* __restrict__ M,
                                                short* __restrict__ Bb) {
  int n = blockIdx.x;   // 0..255
  int k = threadIdx.x;  // 0..255
  Bb[n * 512 + k]       = f2b(W[k * DD + n]);
  Bb[n * 512 + k + 256] = f2b(M[k * DD + n]);
}

__global__ __launch_bounds__(256) void k_hist(const int* __restrict__ dst,
                                              int* __restrict__ deg) {
  int e = blockIdx.x * 256 + threadIdx.x;
  if (e < N_EDGES) atomicAdd(&deg[dst[e]], 1);
}

// exclusive scan of deg[10000] -> rowstart, cursor (single block, 1024 threads x 10)
__global__ __launch_bounds__(1024) void k_scan(const int* __restrict__ deg,
                                               int* __restrict__ rowstart,
                                               int* __restrict__ cursor) {
  __shared__ int wsum[16];
  const int t = threadIdx.x;
  const int base = t * 10;
  int local[10];
  int s = 0;
  #pragma unroll
  for (int i = 0; i < 10; i++) {
    int idx = base + i;
    int dv = (idx < N_NODES) ? deg[idx] : 0;
    local[i] = s;
    s += dv;
  }
  const int lane = t & 63, wv = t >> 6;
  int v = s;
  #pragma unroll
  for (int off = 1; off < 64; off <<= 1) {
    int u = __shfl_up(v, off);
    if (lane >= off) v += u;
  }
  if (lane == 63) wsum[wv] = v;
  __syncthreads();
  if (t < 16) {
    int a = wsum[t];
    int vv = a;
    #pragma unroll
    for (int off = 1; off < 16; off <<= 1) {
      int u = __shfl_up(vv, off);
      if (t >= off) vv += u;
    }
    wsum[t] = vv - a;
  }
  __syncthreads();
  const int excl = (v - s) + wsum[wv];
  #pragma unroll
  for (int i = 0; i < 10; i++) {
    int idx = base + i;
    if (idx < N_NODES) {
      int r = excl + local[i];
      rowstart[idx] = r;
      cursor[idx] = r;
    }
  }
}

__global__ __launch_bounds__(256) void k_scatter(const int* __restrict__ src,
                                                 const int* __restrict__ dst,
                                                 int* __restrict__ cursor,
                                                 int* __restrict__ srcs) {
  int e = blockIdx.x * 256 + threadIdx.x;
  if (e < N_EDGES) {
    int p = atomicAdd(&cursor[dst[e]], 1);
    srcs[p] = src[e];
  }
}

// one wave per node: axb[node] = bf16( sum_{j in N(node)} xb[j] ), f32 accum,
// unroll-8 for 8 independent in-flight gathers (MLP)
__global__ __launch_bounds__(256) void k_agg(const short* __restrict__ xb,
                                             const int* __restrict__ rowstart,
                                             const int* __restrict__ deg,
                                             const int* __restrict__ srcs,
                                             short* __restrict__ axb) {
  const int wave = threadIdx.x >> 6, lane = threadIdx.x & 63;
  const int node = blockIdx.x * 4 + wave;
  const int col = lane * 4;  // 4 bf16 per lane -> 8B loads, 512B per row per wave
  float a0 = 0.f, a1 = 0.f, a2 = 0.f, a3 = 0.f;
  const int rs = rowstart[node];
  const int d = deg[node];
  int e = 0;
  for (; e + 8 <= d; e += 8) {
    int s0 = srcs[rs + e],     s1 = srcs[rs + e + 1];
    int s2 = srcs[rs + e + 2], s3 = srcs[rs + e + 3];
    int s4 = srcs[rs + e + 4], s5 = srcs[rs + e + 5];
    int s6 = srcs[rs + e + 6], s7 = srcs[rs + e + 7];
    short4v v0 = *(const short4v*)(xb + s0 * DD + col);
    short4v v1 = *(const short4v*)(xb + s1 * DD + col);
    short4v v2 = *(const short4v*)(xb + s2 * DD + col);
    short4v v3 = *(const short4v*)(xb + s3 * DD + col);
    short4v v4 = *(const short4v*)(xb + s4 * DD + col);
    short4v v5 = *(const short4v*)(xb + s5 * DD + col);
    short4v v6 = *(const short4v*)(xb + s6 * DD + col);
    short4v v7 = *(const short4v*)(xb + s7 * DD + col);
    a0 += b2f(v0[0]) + b2f(v1[0]) + b2f(v2[0]) + b2f(v3[0])
        + b2f(v4[0]) + b2f(v5[0]) + b2f(v6[0]) + b2f(v7[0]);
    a1 += b2f(v0[1]) + b2f(v1[1]) + b2f(v2[1]) + b2f(v3[1])
        + b2f(v4[1]) + b2f(v5[1]) + b2f(v6[1]) + b2f(v7[1]);
    a2 += b2f(v0[2]) + b2f(v1[2]) + b2f(v2[2]) + b2f(v3[2])
        + b2f(v4[2]) + b2f(v5[2]) + b2f(v6[2]) + b2f(v7[2]);
    a3 += b2f(v0[3]) + b2f(v1[3]) + b2f(v2[3]) + b2f(v3[3])
        + b2f(v4[3]) + b2f(v5[3]) + b2f(v6[3]) + b2f(v7[3]);
  }
  for (; e < d; e++) {
    int s = srcs[rs + e];
    short4v v = *(const short4v*)(xb + s * DD + col);
    a0 += b2f(v[0]); a1 += b2f(v[1]); a2 += b2f(v[2]); a3 += b2f(v[3]);
  }
  short4v o;
  o[0] = f2b(a0); o[1] = f2b(a1); o[2] = f2b(a2); o[3] = f2b(a3);
  *(short4v*)(axb + node * DD + col) = o;
}

// out = relu( [xb | axb] @ Bb^T ), M=10000, N=256, K=512. Tile 64x64, K staged 4x128.
#define LDK 136  // 128 + 8 bf16 pad

__global__ __launch_bounds__(256) void k_gemm(const short* __restrict__ xb,
                                              const short* __restrict__ axb,
                                              const short* __restrict__ Bb,
                                              float* __restrict__ out) {
  __shared__ short As[64 * LDK];
  __shared__ short Bs[64 * LDK];
  const int m0 = blockIdx.x * 64, n0 = blockIdx.y * 64;
  const int tid = threadIdx.x;
  const int wave = tid >> 6, lane = tid & 63;
  const int wr = (wave >> 1) * 32, wc = (wave & 1) * 32;
  const int lr = lane & 15, lk = (lane >> 4) * 8;
  f32x4 acc00 = {0,0,0,0}, acc01 = {0,0,0,0}, acc10 = {0,0,0,0}, acc11 = {0,0,0,0};

  for (int ko = 0; ko < 512; ko += 128) {
    const short* Asrc = (ko < 256) ? xb : axb;
    const int acol = ko & 255;
    #pragma unroll
    for (int c = tid; c < 1024; c += 256) {
      int row = c >> 4, col = (c & 15) * 8;  // 16 chunks/row * 8 = 128 cols
      int gm = m0 + row;
      short8 va = {0,0,0,0,0,0,0,0};
      if (gm < N_NODES) va = *(const short8*)(Asrc + gm * DD + acol + col);
      *(short8*)(&As[row * LDK + col]) = va;
      *(short8*)(&Bs[row * LDK + col]) = *(const short8*)(Bb + (n0 + row) * 512 + ko + col);
    }
    __syncthreads();
    #pragma unroll
    for (int kk = 0; kk < 128; kk += 32) {
      short8 a0 = *(const short8*)(&As[(wr + lr) * LDK + kk + lk]);
      short8 a1 = *(const short8*)(&As[(wr + 16 + lr) * LDK + kk + lk]);
      short8 b0 = *(const short8*)(&Bs[(wc + lr) * LDK + kk + lk]);
      short8 b1 = *(const short8*)(&Bs[(wc + 16 + lr) * LDK + kk + lk]);
      acc00 = __builtin_amdgcn_mfma_f32_16x16x32_bf16(a0, b0, acc00, 0, 0, 0);
      acc01 = __builtin_amdgcn_mfma_f32_16x16x32_bf16(a0, b1, acc01, 0, 0, 0);
      acc10 = __builtin_amdgcn_mfma_f32_16x16x32_bf16(a1, b0, acc10, 0, 0, 0);
      acc11 = __builtin_amdgcn_mfma_f32_16x16x32_bf16(a1, b1, acc11, 0, 0, 0);
    }
    __syncthreads();
  }

  // D layout: col = lane&15, row = (lane>>4)*4 + reg  [verified m89/m91]
  const int rb = (lane >> 4) * 4;
  const int cb = lane & 15;
  #pragma unroll
  for (int r = 0; r < 4; r++) {
    int gm0 = m0 + wr + rb + r;
    int gm1 = gm0 + 16;
    int gc = n0 + wc + cb;
    if (gm0 < N_NODES) {
      out[gm0 * DD + gc]      = fmaxf(acc00[r], 0.f);
      out[gm0 * DD + gc + 16] = fmaxf(acc01[r], 0.f);
    }
    if (gm1 < N_NODES) {
      out[gm1 * DD + gc]      = fmaxf(acc10[r], 0.f);
      out[gm1 * DD + gc + 16] = fmaxf(acc11[r], 0.f);
    }
  }
}

extern "C" void kernel_launch(void* const* d_in, const int* in_sizes, int n_in,
                              void* d_out, int out_size, void* d_ws, size_t ws_size,
                              hipStream_t stream) {
  const float* x = (const float*)d_in[0];
  const float* W = (const float*)d_in[1];
  const float* M = (const float*)d_in[2];
  const int* esrc = (const int*)d_in[3];
  const int* edst = (const int*)d_in[4];
  float* out = (float*)d_out;

  char* w = (char*)d_ws;
  short* xb  = (short*)w;                   // 10000*256*2 = 5,120,000 B
  short* axb = (short*)(w + 5120000);       // 10000*256*2 = 5,120,000 B
  short* Bb  = (short*)(w + 10240000);      // 256*512*2   =   262,144 B
  int* deg      = (int*)(w + 10502144);     // 40,000 B
  int* rowstart = deg + N_NODES;            // 40,000 B
  int* cursor   = rowstart + N_NODES;       // 40,000 B
  int* srcs     = cursor + N_NODES;         // 1,280,000 B  (total ~11.9 MB)

  hipMemsetAsync(deg, 0, N_NODES * sizeof(int), stream);
  k_conv_x<<<2500, 256, 0, stream>>>(x, xb);
  k_conv_B<<<256, 256, 0, stream>>>(W, M, Bb);
  k_hist<<<1250, 256, 0, stream>>>(edst, deg);
  k_scan<<<1, 1024, 0, stream>>>(deg, rowstart, cursor);
  k_scatter<<<1250, 256, 0, stream>>>(esrc, edst, cursor, srcs);
  k_agg<<<2500, 256, 0, stream>>>(xb, rowstart, deg, srcs, axb);
  k_gemm<<<dim3(157, 4), 256, 0, stream>>>(xb, axb, Bb, out);
}